// Round 1
// baseline (1074.733 us; speedup 1.0000x reference)
//
#include <hip/hip_runtime.h>

#define L_  1024
#define D_  64
#define TM  128
#define TN  64
#define NT  (L_ / TN)

typedef __attribute__((ext_vector_type(8))) short          short8;
typedef __attribute__((ext_vector_type(8))) unsigned short ushort8;
typedef __attribute__((ext_vector_type(4))) float          f32x4;

__device__ __forceinline__ unsigned short bf16r(float f) {
    unsigned u = __builtin_bit_cast(unsigned, f);
    u += 0x7fffu + ((u >> 16) & 1u);          // round-to-nearest-even
    return (unsigned short)(u >> 16);
}

// XOR-swizzled index (ushort units) into a 64-col (128 B-row) LDS tile.
// 16-B slot index XORed with row&7: row-strided 16-lane reads land on 8
// distinct slots (rows r and r+8 alias -> 2-way, free per m136).
__device__ __forceinline__ int swz(int row, int colu) {
    return row * 64 + ((((colu >> 3) ^ row) & 7) << 3) + (colu & 7);
}

__global__ __launch_bounds__(256, 3)
void sdpa_kernel(const float* __restrict__ q, const float* __restrict__ kmat,
                 const float* __restrict__ v, float* __restrict__ out,
                 float* __restrict__ attn)
{
    __shared__ __align__(16) unsigned short Qs[TM * 64];   // Q[m][k]    bf16, swizzled
    __shared__ __align__(16) unsigned short Ks[TN * 64];   // Kt^T[n][k] bf16, swizzled
    __shared__ __align__(16) unsigned short Vs[D_ * 64];   // V^T[c][n'] bf16, swizzled
    __shared__ __align__(16) unsigned short Ps[TM * 64];   // P[m][n']   bf16, swizzled
    // total 48 KB -> 3 blocks/CU (was 54 KB -> 2)

    const int t    = threadIdx.x;
    const int lane = t & 63;
    const int wave = t >> 6;
    const int quad = lane >> 4;
    const int l15  = lane & 15;
    const int rt   = blockIdx.x;          // row tile 0..7
    const int bh   = blockIdx.y;          // 0..127
    const int m0   = rt * TM;
    const int rowA = wave * 32;           // this wave's rows within tile

    const float* qb = q    + (size_t)bh * (L_ * D_);
    const float* kb = kmat + (size_t)bh * (L_ * D_);   // Kt[kk][n] at kk*1024+n (reshape!)
    const float* vb = v    + (size_t)bh * (L_ * D_);
    float* outb  = out  + (size_t)bh * (L_ * D_);
    float* attnb = attn + (size_t)bh * ((size_t)L_ * L_);

    // ---- stage Q tile (once): coalesced float4, cvt bf16 ----
    #pragma unroll
    for (int i = 0; i < 8; ++i) {
        int idx = (i * 256 + t) * 4;            // 0..8191
        int m = idx >> 6, c = idx & 63;
        float4 f = *(const float4*)&qb[(size_t)(m0 + m) * D_ + c];
        ushort4 b;
        b.x = bf16r(f.x); b.y = bf16r(f.y); b.z = bf16r(f.z); b.w = bf16r(f.w);
        *(ushort4*)&Qs[swz(m, c)] = b;
    }

    // ---- reg-staged K/V prefetch (T14: issue-early / write-late) ----
    float2 rK[8], rV[8];
    const int ng = t & 31, kg = t >> 5;   // same decomposition for K and V staging

    auto loadK = [&](int nt) {
        const float* src = kb + (size_t)(kg * 8) * L_ + nt * TN + 2 * ng;
        #pragma unroll
        for (int j = 0; j < 8; ++j) rK[j] = *(const float2*)(src + (size_t)j * L_);
    };
    auto writeK = [&]() {
        ushort8 r0, r1;
        #pragma unroll
        for (int j = 0; j < 8; ++j) { r0[j] = bf16r(rK[j].x); r1[j] = bf16r(rK[j].y); }
        *(ushort8*)&Ks[swz(2 * ng,     kg * 8)] = r0;
        *(ushort8*)&Ks[swz(2 * ng + 1, kg * 8)] = r1;
    };
    auto loadV = [&](int nt) {
        const float* src = vb + (size_t)(nt * TN + kg * 8) * D_ + 2 * ng;
        #pragma unroll
        for (int j = 0; j < 8; ++j) rV[j] = *(const float2*)(src + (size_t)j * D_);
    };
    auto writeV = [&]() {
        ushort8 r0, r1;
        #pragma unroll
        for (int j = 0; j < 8; ++j) { r0[j] = bf16r(rV[j].x); r1[j] = bf16r(rV[j].y); }
        *(ushort8*)&Vs[swz(2 * ng,     kg * 8)] = r0;
        *(ushort8*)&Vs[swz(2 * ng + 1, kg * 8)] = r1;
    };

    auto computeScore = [&](f32x4 (&acc)[2][4]) {
        #pragma unroll
        for (int ks = 0; ks < 2; ++ks) {
            const int cu = ks * 32 + quad * 8;
            short8 af[2];
            #pragma unroll
            for (int tr = 0; tr < 2; ++tr)
                af[tr] = *(const short8*)&Qs[swz(rowA + tr * 16 + l15, cu)];
            #pragma unroll
            for (int tc = 0; tc < 4; ++tc) {
                short8 bfr = *(const short8*)&Ks[swz(tc * 16 + l15, cu)];
                #pragma unroll
                for (int tr = 0; tr < 2; ++tr)
                    acc[tr][tc] = __builtin_amdgcn_mfma_f32_16x16x32_bf16(af[tr], bfr, acc[tr][tc], 0, 0, 0);
            }
        }
    };

    const f32x4 zero4 = {0.f, 0.f, 0.f, 0.f};

    // ================= Phase 1: row sums Z (triangular sweep) =================
    float zpart[2][4] = {};
    const int ntmax1 = (m0 + TM - 1) / TN;      // last tile touching the diagonal
    loadK(0);
    for (int nt = 0; nt <= ntmax1; ++nt) {
        __syncthreads();                        // prev readers done (iter0: Qs staged)
        writeK();
        if (nt < ntmax1) loadK(nt + 1);         // hide next load under compute
        __syncthreads();
        f32x4 acc[2][4];
        #pragma unroll
        for (int tr = 0; tr < 2; ++tr)
            #pragma unroll
            for (int tc = 0; tc < 4; ++tc) acc[tr][tc] = zero4;
        computeScore(acc);
        #pragma unroll
        for (int tr = 0; tr < 2; ++tr)
            #pragma unroll
            for (int r = 0; r < 4; ++r) {
                const int gm = m0 + rowA + tr * 16 + quad * 4 + r;
                #pragma unroll
                for (int tc = 0; tc < 4; ++tc) {
                    const int gn = nt * TN + tc * 16 + l15;
                    zpart[tr][r] += (gn > gm) ? 1.0f : __expf(acc[tr][tc][r] * 0.125f);
                }
            }
    }
    // Masked columns in tiles nt > ntmax1: each contributes exp(-1e-12) == 1.0f.
    const float zmissing = (float)(L_ - (ntmax1 + 1) * TN);

    // preload phase-2 tile 0 while the z-reduction runs
    loadV(0);
    loadK(0);                                   // fullmask(0) is always false

    float rcpz[2][4];
    #pragma unroll
    for (int tr = 0; tr < 2; ++tr)
        #pragma unroll
        for (int r = 0; r < 4; ++r) {
            float z = zpart[tr][r];
            z += __shfl_xor(z, 1);
            z += __shfl_xor(z, 2);
            z += __shfl_xor(z, 4);
            z += __shfl_xor(z, 8);
            rcpz[tr][r] = 1.0f / (z + zmissing);
        }

    // ================= Phase 2: write attn, accumulate out = P @ V =================
    f32x4 oacc[2][4];
    #pragma unroll
    for (int tr = 0; tr < 2; ++tr)
        #pragma unroll
        for (int tc = 0; tc < 4; ++tc) oacc[tr][tc] = zero4;

    for (int nt = 0; nt < NT; ++nt) {
        const bool fullmask = (nt * TN) > (m0 + TM - 1);   // block-uniform
        __syncthreads();                        // all waves done reading Ks/Vs/Ps
        writeV();
        if (!fullmask) writeK();
        const int nn = nt + 1;
        if (nn < NT) {                          // prefetch next tile under compute
            loadV(nn);
            if ((nn * TN) <= (m0 + TM - 1)) loadK(nn);
        }
        __syncthreads();                        // staging visible

        if (!fullmask) {
            f32x4 acc[2][4];
            #pragma unroll
            for (int tr = 0; tr < 2; ++tr)
                #pragma unroll
                for (int tc = 0; tc < 4; ++tc) acc[tr][tc] = zero4;
            computeScore(acc);
            #pragma unroll
            for (int tr = 0; tr < 2; ++tr)
                #pragma unroll
                for (int r = 0; r < 4; ++r) {
                    const int lrow = rowA + tr * 16 + quad * 4 + r;
                    const int gm = m0 + lrow;
                    #pragma unroll
                    for (int tc = 0; tc < 4; ++tc) {
                        const int gn = nt * TN + tc * 16 + l15;
                        float e = (gn > gm) ? 1.0f : __expf(acc[tr][tc][r] * 0.125f);
                        float p = e * rcpz[tr][r];
                        attnb[(size_t)gm * L_ + gn] = p;       // fp32 attn output
                        Ps[swz(lrow, tc * 16 + l15)] = bf16r(p);
                    }
                }
        } else {
            // row-constant value 1/Z: vectorized broadcast stores
            #pragma unroll
            for (int tr = 0; tr < 2; ++tr)
                #pragma unroll
                for (int r = 0; r < 4; ++r) {
                    const int lrow = rowA + tr * 16 + quad * 4 + r;
                    const int gm = m0 + lrow;
                    const float rz = rcpz[tr][r];
                    float4 vv = {rz, rz, rz, rz};
                    *(float4*)&attnb[(size_t)gm * L_ + nt * TN + 4 * l15] = vv;
                    const unsigned short pb = bf16r(rz);
                    ushort4 p4; p4.x = pb; p4.y = pb; p4.z = pb; p4.w = pb;
                    *(ushort4*)&Ps[swz(lrow, 4 * l15)] = p4;
                }
        }

        // Ps rows read below were written by THIS wave only -> no __syncthreads
        asm volatile("s_waitcnt lgkmcnt(0)" ::: "memory");
        __builtin_amdgcn_sched_barrier(0);

        #pragma unroll
        for (int ks = 0; ks < 2; ++ks) {
            const int cu = ks * 32 + quad * 8;
            short8 pf[2];
            #pragma unroll
            for (int tr = 0; tr < 2; ++tr)
                pf[tr] = *(const short8*)&Ps[swz(rowA + tr * 16 + l15, cu)];
            #pragma unroll
            for (int tc = 0; tc < 4; ++tc) {
                short8 vf = *(const short8*)&Vs[swz(tc * 16 + l15, cu)];
                #pragma unroll
                for (int tr = 0; tr < 2; ++tr)
                    oacc[tr][tc] = __builtin_amdgcn_mfma_f32_16x16x32_bf16(pf[tr], vf, oacc[tr][tc], 0, 0, 0);
            }
        }
    }

    // epilogue: store out (already normalized)
    #pragma unroll
    for (int tr = 0; tr < 2; ++tr)
        #pragma unroll
        for (int r = 0; r < 4; ++r) {
            const int gm = m0 + rowA + tr * 16 + quad * 4 + r;
            #pragma unroll
            for (int tc = 0; tc < 4; ++tc)
                outb[(size_t)gm * D_ + tc * 16 + l15] = oacc[tr][tc][r];
        }
}

extern "C" void kernel_launch(void* const* d_in, const int* in_sizes, int n_in,
                              void* d_out, int out_size, void* d_ws, size_t ws_size,
                              hipStream_t stream) {
    (void)in_sizes; (void)n_in; (void)d_ws; (void)ws_size; (void)out_size;
    const float* q = (const float*)d_in[0];
    const float* k = (const float*)d_in[1];
    const float* v = (const float*)d_in[2];
    // d_in[3] is the mask: it is tril(L,L) by construction; gn>gm reproduces it exactly.
    float* out  = (float*)d_out;
    float* attn = (float*)d_out + (size_t)8 * 16 * 1024 * 64;   // outputs concatenated (out, attn)
    dim3 grid(8, 128);
    sdpa_kernel<<<grid, dim3(256), 0, stream>>>(q, k, v, out, attn);
}

// Round 2
// 976.400 us; speedup vs baseline: 1.1007x; 1.1007x over previous
//
#include <hip/hip_runtime.h>

#define L_  1024
#define D_  64
#define TM  128
#define TN  64
#define NT  (L_ / TN)

typedef __attribute__((ext_vector_type(8))) short          short8;
typedef __attribute__((ext_vector_type(8))) unsigned short ushort8;
typedef __attribute__((ext_vector_type(4))) float          f32x4;

__device__ __forceinline__ unsigned short bf16r(float f) {
    unsigned u = __builtin_bit_cast(unsigned, f);
    u += 0x7fffu + ((u >> 16) & 1u);          // round-to-nearest-even
    return (unsigned short)(u >> 16);
}

// XOR-swizzled index (ushort units) into a 64-col (128 B-row) LDS tile.
// 16-B slot index XORed with row&7: row-strided 16-lane reads land on 8
// distinct slots (rows r and r+8 alias -> 2-way, free per m136).
// Purpose: drop the +8 pad -> 48 KB total LDS -> 3 blocks/CU.
__device__ __forceinline__ int swz(int row, int colu) {
    return row * 64 + ((((colu >> 3) ^ row) & 7) << 3) + (colu & 7);
}

__global__ __launch_bounds__(256, 3)
void sdpa_kernel(const float* __restrict__ q, const float* __restrict__ kmat,
                 const float* __restrict__ v, float* __restrict__ out,
                 float* __restrict__ attn)
{
    __shared__ __align__(16) unsigned short Qs[TM * 64];   // Q[m][k]    bf16, swizzled
    __shared__ __align__(16) unsigned short Ks[TN * 64];   // Kt^T[n][k] bf16, swizzled
    __shared__ __align__(16) unsigned short Vs[D_ * 64];   // V^T[c][n'] bf16, swizzled
    __shared__ __align__(16) unsigned short Ps[TM * 64];   // P[m][n']   bf16, swizzled
    // total 48 KB -> 3 blocks/CU

    const int t    = threadIdx.x;
    const int lane = t & 63;
    const int wave = t >> 6;
    const int quad = lane >> 4;
    const int l15  = lane & 15;
    const int rt   = blockIdx.x;          // row tile 0..7
    const int bh   = blockIdx.y;          // 0..127
    const int m0   = rt * TM;
    const int rowA = wave * 32;           // this wave's rows within tile

    const float* qb = q    + (size_t)bh * (L_ * D_);
    const float* kb = kmat + (size_t)bh * (L_ * D_);   // Kt[kk][n] at kk*1024+n (reshape!)
    const float* vb = v    + (size_t)bh * (L_ * D_);
    float* outb  = out  + (size_t)bh * (L_ * D_);
    float* attnb = attn + (size_t)bh * ((size_t)L_ * L_);

    // ---- stage Q tile (once): coalesced float4, cvt bf16 ----
    #pragma unroll
    for (int i = 0; i < 8; ++i) {
        int idx = (i * 256 + t) * 4;            // 0..8191
        int m = idx >> 6, c = idx & 63;
        float4 f = *(const float4*)&qb[(size_t)(m0 + m) * D_ + c];
        ushort4 b;
        b.x = bf16r(f.x); b.y = bf16r(f.y); b.z = bf16r(f.z); b.w = bf16r(f.w);
        *(ushort4*)&Qs[swz(m, c)] = b;
    }

    // ---- staging lambdas (micro-transpose 8k x 2n per thread, inline load->write) ----
    auto stageK = [&](int nt) {
        const int ng = t & 31, kg = t >> 5;     // n = 2*ng, kk0 = 8*kg
        const float* src = kb + (size_t)(kg * 8) * L_ + nt * TN + 2 * ng;
        float2 a[8];
        #pragma unroll
        for (int j = 0; j < 8; ++j) a[j] = *(const float2*)(src + (size_t)j * L_);
        ushort8 r0, r1;
        #pragma unroll
        for (int j = 0; j < 8; ++j) { r0[j] = bf16r(a[j].x); r1[j] = bf16r(a[j].y); }
        *(ushort8*)&Ks[swz(2 * ng,     kg * 8)] = r0;
        *(ushort8*)&Ks[swz(2 * ng + 1, kg * 8)] = r1;
    };
    auto stageV = [&](int nt) {
        const int cg = t & 31, ngp = t >> 5;    // c = 2*cg, n0 = 8*ngp
        const float* src = vb + (size_t)(nt * TN + ngp * 8) * D_ + 2 * cg;
        float2 a[8];
        #pragma unroll
        for (int j = 0; j < 8; ++j) a[j] = *(const float2*)(src + (size_t)j * D_);
        ushort8 r0, r1;
        #pragma unroll
        for (int j = 0; j < 8; ++j) { r0[j] = bf16r(a[j].x); r1[j] = bf16r(a[j].y); }
        *(ushort8*)&Vs[swz(2 * cg,     ngp * 8)] = r0;
        *(ushort8*)&Vs[swz(2 * cg + 1, ngp * 8)] = r1;
    };

    auto computeScore = [&](f32x4 (&acc)[2][4]) {
        #pragma unroll
        for (int ks = 0; ks < 2; ++ks) {
            const int cu = ks * 32 + quad * 8;
            short8 af[2];
            #pragma unroll
            for (int tr = 0; tr < 2; ++tr)
                af[tr] = *(const short8*)&Qs[swz(rowA + tr * 16 + l15, cu)];
            #pragma unroll
            for (int tc = 0; tc < 4; ++tc) {
                short8 bfr = *(const short8*)&Ks[swz(tc * 16 + l15, cu)];
                #pragma unroll
                for (int tr = 0; tr < 2; ++tr)
                    acc[tr][tc] = __builtin_amdgcn_mfma_f32_16x16x32_bf16(af[tr], bfr, acc[tr][tc], 0, 0, 0);
            }
        }
    };

    const f32x4 zero4 = {0.f, 0.f, 0.f, 0.f};

    // ================= Phase 1: row sums Z (triangular sweep) =================
    float zpart[2][4] = {};
    const int ntmax1 = (m0 + TM - 1) / TN;      // last tile touching the diagonal
    __syncthreads();                            // Qs visible
    for (int nt = 0; nt <= ntmax1; ++nt) {
        stageK(nt);
        __syncthreads();
        f32x4 acc[2][4];
        #pragma unroll
        for (int tr = 0; tr < 2; ++tr)
            #pragma unroll
            for (int tc = 0; tc < 4; ++tc) acc[tr][tc] = zero4;
        computeScore(acc);
        #pragma unroll
        for (int tr = 0; tr < 2; ++tr)
            #pragma unroll
            for (int r = 0; r < 4; ++r) {
                const int gm = m0 + rowA + tr * 16 + quad * 4 + r;
                #pragma unroll
                for (int tc = 0; tc < 4; ++tc) {
                    const int gn = nt * TN + tc * 16 + l15;
                    zpart[tr][r] += (gn > gm) ? 1.0f : __expf(acc[tr][tc][r] * 0.125f);
                }
            }
        __syncthreads();                        // protect Ks before next stage
    }
    // Masked columns in tiles nt > ntmax1 never visited above: each contributes
    // exp(-1e-12) == 1.0f to the softmax denominator. Block-uniform count.
    const float zmissing = (float)(L_ - (ntmax1 + 1) * TN);
    float rcpz[2][4];
    #pragma unroll
    for (int tr = 0; tr < 2; ++tr)
        #pragma unroll
        for (int r = 0; r < 4; ++r) {
            float z = zpart[tr][r];
            z += __shfl_xor(z, 1);
            z += __shfl_xor(z, 2);
            z += __shfl_xor(z, 4);
            z += __shfl_xor(z, 8);
            rcpz[tr][r] = 1.0f / (z + zmissing);
        }

    // ================= Phase 2: write attn, accumulate out = P @ V =================
    f32x4 oacc[2][4];
    #pragma unroll
    for (int tr = 0; tr < 2; ++tr)
        #pragma unroll
        for (int tc = 0; tc < 4; ++tc) oacc[tr][tc] = zero4;

    for (int nt = 0; nt < NT; ++nt) {
        const bool fullmask = (nt * TN) > (m0 + TM - 1);   // block-uniform
        __syncthreads();                                   // prev iter done with Ks/Vs/Ps
        if (!fullmask) stageK(nt);
        stageV(nt);
        __syncthreads();

        if (!fullmask) {
            f32x4 acc[2][4];
            #pragma unroll
            for (int tr = 0; tr < 2; ++tr)
                #pragma unroll
                for (int tc = 0; tc < 4; ++tc) acc[tr][tc] = zero4;
            computeScore(acc);
            #pragma unroll
            for (int tr = 0; tr < 2; ++tr)
                #pragma unroll
                for (int r = 0; r < 4; ++r) {
                    const int lrow = rowA + tr * 16 + quad * 4 + r;
                    const int gm = m0 + lrow;
                    #pragma unroll
                    for (int tc = 0; tc < 4; ++tc) {
                        const int gn = nt * TN + tc * 16 + l15;
                        float e = (gn > gm) ? 1.0f : __expf(acc[tr][tc][r] * 0.125f);
                        float p = e * rcpz[tr][r];
                        attnb[(size_t)gm * L_ + gn] = p;       // fp32 attn output
                        Ps[swz(lrow, tc * 16 + l15)] = bf16r(p);
                    }
                }
        } else {
            // row-constant value 1/Z: vectorized broadcast stores
            #pragma unroll
            for (int tr = 0; tr < 2; ++tr)
                #pragma unroll
                for (int r = 0; r < 4; ++r) {
                    const int lrow = rowA + tr * 16 + quad * 4 + r;
                    const int gm = m0 + lrow;
                    const float rz = rcpz[tr][r];
                    float4 vv = {rz, rz, rz, rz};
                    *(float4*)&attnb[(size_t)gm * L_ + nt * TN + 4 * l15] = vv;
                    const unsigned short pb = bf16r(rz);
                    ushort4 p4; p4.x = pb; p4.y = pb; p4.z = pb; p4.w = pb;
                    *(ushort4*)&Ps[swz(lrow, 4 * l15)] = p4;
                }
        }
        __syncthreads();                                   // Ps ready

        #pragma unroll
        for (int ks = 0; ks < 2; ++ks) {
            const int cu = ks * 32 + quad * 8;
            short8 pf[2];
            #pragma unroll
            for (int tr = 0; tr < 2; ++tr)
                pf[tr] = *(const short8*)&Ps[swz(rowA + tr * 16 + l15, cu)];
            #pragma unroll
            for (int tc = 0; tc < 4; ++tc) {
                short8 vf = *(const short8*)&Vs[swz(tc * 16 + l15, cu)];
                #pragma unroll
                for (int tr = 0; tr < 2; ++tr)
                    oacc[tr][tc] = __builtin_amdgcn_mfma_f32_16x16x32_bf16(pf[tr], vf, oacc[tr][tc], 0, 0, 0);
            }
        }
    }

    // epilogue: store out (already normalized)
    #pragma unroll
    for (int tr = 0; tr < 2; ++tr)
        #pragma unroll
        for (int r = 0; r < 4; ++r) {
            const int gm = m0 + rowA + tr * 16 + quad * 4 + r;
            #pragma unroll
            for (int tc = 0; tc < 4; ++tc)
                outb[(size_t)gm * D_ + tc * 16 + l15] = oacc[tr][tc][r];
        }
}

extern "C" void kernel_launch(void* const* d_in, const int* in_sizes, int n_in,
                              void* d_out, int out_size, void* d_ws, size_t ws_size,
                              hipStream_t stream) {
    (void)in_sizes; (void)n_in; (void)d_ws; (void)ws_size; (void)out_size;
    const float* q = (const float*)d_in[0];
    const float* k = (const float*)d_in[1];
    const float* v = (const float*)d_in[2];
    // d_in[3] is the mask: it is tril(L,L) by construction; gn>gm reproduces it exactly.
    float* out  = (float*)d_out;
    float* attn = (float*)d_out + (size_t)8 * 16 * 1024 * 64;   // outputs concatenated (out, attn)
    dim3 grid(8, 128);
    sdpa_kernel<<<grid, dim3(256), 0, stream>>>(q, k, v, out, attn);
}

// Round 3
// 783.170 us; speedup vs baseline: 1.3723x; 1.2467x over previous
//
#include <hip/hip_runtime.h>

#define L_  1024
#define D_  64
#define TM  128
#define TN  64
#define LDK 72            // padded ushort stride (64 + 8) -> 144 B rows, 16B-aligned
#define NT  (L_ / TN)

typedef __attribute__((ext_vector_type(8))) short          short8;
typedef __attribute__((ext_vector_type(8))) unsigned short ushort8;
typedef __attribute__((ext_vector_type(4))) float          f32x4;

__device__ __forceinline__ unsigned short bf16r(float f) {
    unsigned u = __builtin_bit_cast(unsigned, f);
    u += 0x7fffu + ((u >> 16) & 1u);          // round-to-nearest-even
    return (unsigned short)(u >> 16);
}

__global__ __launch_bounds__(256, 2)
void sdpa_kernel(const float* __restrict__ q, const float* __restrict__ kmat,
                 const float* __restrict__ v, float* __restrict__ out,
                 float* __restrict__ attn)
{
    __shared__ __align__(16) unsigned short Qs[TM * LDK];   // Q[m][k]   bf16
    __shared__ __align__(16) unsigned short Ks[TN * LDK];   // Kt^T[n][k] bf16 (n-major)
    __shared__ __align__(16) unsigned short Vs[D_ * LDK];   // V^T[c][n'] bf16 (c-major)
    __shared__ __align__(16) unsigned short Ps[TM * LDK];   // P[m][n']  bf16

    const int t    = threadIdx.x;
    const int wave = t >> 6;
    const int lane = t & 63;
    const int quad = lane >> 4;
    const int l15  = lane & 15;
    const int rt   = blockIdx.x;          // row tile 0..7
    const int bh   = blockIdx.y;          // 0..127
    const int m0   = rt * TM;
    const int rowA = wave * 32;           // this wave's rows within tile

    const float* qb = q    + (size_t)bh * (L_ * D_);
    const float* kb = kmat + (size_t)bh * (L_ * D_);   // Kt[kk][n] at kk*1024+n (reshape!)
    const float* vb = v    + (size_t)bh * (L_ * D_);
    float* outb  = out  + (size_t)bh * (L_ * D_);
    float* attnb = attn + (size_t)bh * ((size_t)L_ * L_);

    // ---- stage Q tile (once): coalesced float4, cvt bf16 ----
    #pragma unroll
    for (int i = 0; i < 8; ++i) {
        int idx = (i * 256 + t) * 4;            // 0..8191
        int m = idx >> 6, c = idx & 63;
        float4 f = *(const float4*)&qb[(size_t)(m0 + m) * D_ + c];
        ushort4 b;
        b.x = bf16r(f.x); b.y = bf16r(f.y); b.z = bf16r(f.z); b.w = bf16r(f.w);
        *(ushort4*)&Qs[m * LDK + c] = b;
    }

    // ---- staging lambdas (micro-transpose 8k x 2n per thread) ----
    auto stageK = [&](int nt) {
        const int ng = t & 31, kg = t >> 5;     // n = 2*ng, kk0 = 8*kg
        const float* src = kb + (size_t)(kg * 8) * L_ + nt * TN + 2 * ng;
        float2 a[8];
        #pragma unroll
        for (int j = 0; j < 8; ++j) a[j] = *(const float2*)(src + (size_t)j * L_);
        ushort8 r0, r1;
        #pragma unroll
        for (int j = 0; j < 8; ++j) { r0[j] = bf16r(a[j].x); r1[j] = bf16r(a[j].y); }
        *(ushort8*)&Ks[(2 * ng)     * LDK + kg * 8] = r0;
        *(ushort8*)&Ks[(2 * ng + 1) * LDK + kg * 8] = r1;
    };
    auto stageV = [&](int nt) {
        const int cg = t & 31, ngp = t >> 5;    // c = 2*cg, n0 = 8*ngp
        const float* src = vb + (size_t)(nt * TN + ngp * 8) * D_ + 2 * cg;
        float2 a[8];
        #pragma unroll
        for (int j = 0; j < 8; ++j) a[j] = *(const float2*)(src + (size_t)j * D_);
        ushort8 r0, r1;
        #pragma unroll
        for (int j = 0; j < 8; ++j) { r0[j] = bf16r(a[j].x); r1[j] = bf16r(a[j].y); }
        *(ushort8*)&Vs[(2 * cg)     * LDK + ngp * 8] = r0;
        *(ushort8*)&Vs[(2 * cg + 1) * LDK + ngp * 8] = r1;
    };

    // Transposed score: acc[tr][tc] = S^T tile -> lane holds row m = (tr*16+l15),
    // cols n = tc*16 + quad*4 + r. Same LDS reads as before; operands SWAPPED.
    auto computeScoreT = [&](f32x4 (&acc)[2][4]) {
        #pragma unroll
        for (int ks = 0; ks < 2; ++ks) {
            const int cu = ks * 32 + quad * 8;
            short8 af[2];
            #pragma unroll
            for (int tr = 0; tr < 2; ++tr)
                af[tr] = *(const short8*)&Qs[(rowA + tr * 16 + l15) * LDK + cu];
            #pragma unroll
            for (int tc = 0; tc < 4; ++tc) {
                short8 bfr = *(const short8*)&Ks[(tc * 16 + l15) * LDK + cu];
                #pragma unroll
                for (int tr = 0; tr < 2; ++tr)
                    acc[tr][tc] = __builtin_amdgcn_mfma_f32_16x16x32_bf16(bfr, af[tr], acc[tr][tc], 0, 0, 0);
            }
        }
    };

    const f32x4 zero4 = {0.f, 0.f, 0.f, 0.f};

    // ================= Phase 1: row sums Z (triangular sweep) =================
    float zrow[2] = {0.f, 0.f};                 // this lane's row (per tr) partial sum
    const int ntmax1 = (m0 + TM - 1) / TN;      // last tile touching the diagonal
    __syncthreads();                            // Qs visible
    for (int nt = 0; nt <= ntmax1; ++nt) {
        stageK(nt);
        __syncthreads();
        f32x4 acc[2][4];
        #pragma unroll
        for (int tr = 0; tr < 2; ++tr)
            #pragma unroll
            for (int tc = 0; tc < 4; ++tc) acc[tr][tc] = zero4;
        computeScoreT(acc);
        #pragma unroll
        for (int tr = 0; tr < 2; ++tr) {
            const int gm = m0 + rowA + tr * 16 + l15;
            #pragma unroll
            for (int tc = 0; tc < 4; ++tc)
                #pragma unroll
                for (int r = 0; r < 4; ++r) {
                    const int gn = nt * TN + tc * 16 + quad * 4 + r;
                    zrow[tr] += (gn > gm) ? 1.0f : __expf(acc[tr][tc][r] * 0.125f);
                }
        }
        __syncthreads();                        // protect Ks before next stage
    }
    // Masked columns in tiles nt > ntmax1 never visited above: each contributes
    // exp(-1e-12) == 1.0f to the softmax denominator. Block-uniform count.
    const float zmissing = (float)(L_ - (ntmax1 + 1) * TN);
    float rcpz[2];
    #pragma unroll
    for (int tr = 0; tr < 2; ++tr) {
        float z = zrow[tr];
        z += __shfl_xor(z, 16);                 // sum across quads (same l15)
        z += __shfl_xor(z, 32);
        rcpz[tr] = 1.0f / (z + zmissing);
    }

    // ================= Phase 2: write attn, accumulate out = P @ V =================
    f32x4 oacc[2][4];
    #pragma unroll
    for (int tr = 0; tr < 2; ++tr)
        #pragma unroll
        for (int tc = 0; tc < 4; ++tc) oacc[tr][tc] = zero4;

    for (int nt = 0; nt < NT; ++nt) {
        const bool fullmask = (nt * TN) > (m0 + TM - 1);   // block-uniform
        __syncthreads();                                   // prev iter done with Ks/Vs/Ps
        if (!fullmask) stageK(nt);
        stageV(nt);
        __syncthreads();

        if (!fullmask) {
            f32x4 acc[2][4];
            #pragma unroll
            for (int tr = 0; tr < 2; ++tr)
                #pragma unroll
                for (int tc = 0; tc < 4; ++tc) acc[tr][tc] = zero4;
            computeScoreT(acc);
            #pragma unroll
            for (int tr = 0; tr < 2; ++tr) {
                const int lrow = rowA + tr * 16 + l15;
                const int gm = m0 + lrow;
                const float rz = rcpz[tr];
                #pragma unroll
                for (int tc = 0; tc < 4; ++tc) {
                    float p[4];
                    #pragma unroll
                    for (int r = 0; r < 4; ++r) {
                        const int gn = nt * TN + tc * 16 + quad * 4 + r;
                        float e = (gn > gm) ? 1.0f : __expf(acc[tr][tc][r] * 0.125f);
                        p[r] = e * rz;
                    }
                    float4 vv = {p[0], p[1], p[2], p[3]};
                    *(float4*)&attnb[(size_t)gm * L_ + nt * TN + tc * 16 + quad * 4] = vv;
                    ushort4 pw;
                    pw.x = bf16r(p[0]); pw.y = bf16r(p[1]);
                    pw.z = bf16r(p[2]); pw.w = bf16r(p[3]);
                    *(ushort4*)&Ps[lrow * LDK + tc * 16 + quad * 4] = pw;
                }
            }
        } else {
            // row-constant value 1/Z: broadcast stores; Ps content is nt-invariant
            const bool firstFull = (nt == ntmax1 + 1);
            #pragma unroll
            for (int tr = 0; tr < 2; ++tr) {
                const int lrow = rowA + tr * 16 + l15;
                const int gm = m0 + lrow;
                const float rz = rcpz[tr];
                float4 vv = {rz, rz, rz, rz};
                const unsigned short pb = bf16r(rz);
                ushort4 p4; p4.x = pb; p4.y = pb; p4.z = pb; p4.w = pb;
                #pragma unroll
                for (int c = 0; c < 4; ++c) {
                    *(float4*)&attnb[(size_t)gm * L_ + nt * TN + c * 16 + quad * 4] = vv;
                    if (firstFull)
                        *(ushort4*)&Ps[lrow * LDK + c * 16 + quad * 4] = p4;
                }
            }
        }
        __syncthreads();                                   // Ps ready

        #pragma unroll
        for (int ks = 0; ks < 2; ++ks) {
            const int cu = ks * 32 + quad * 8;
            short8 pf[2];
            #pragma unroll
            for (int tr = 0; tr < 2; ++tr)
                pf[tr] = *(const short8*)&Ps[(rowA + tr * 16 + l15) * LDK + cu];
            #pragma unroll
            for (int tc = 0; tc < 4; ++tc) {
                short8 vf = *(const short8*)&Vs[(tc * 16 + l15) * LDK + cu];
                #pragma unroll
                for (int tr = 0; tr < 2; ++tr)
                    oacc[tr][tc] = __builtin_amdgcn_mfma_f32_16x16x32_bf16(pf[tr], vf, oacc[tr][tc], 0, 0, 0);
            }
        }
    }

    // epilogue: store out (already normalized)
    #pragma unroll
    for (int tr = 0; tr < 2; ++tr)
        #pragma unroll
        for (int r = 0; r < 4; ++r) {
            const int gm = m0 + rowA + tr * 16 + quad * 4 + r;
            #pragma unroll
            for (int tc = 0; tc < 4; ++tc)
                outb[(size_t)gm * D_ + tc * 16 + l15] = oacc[tr][tc][r];
        }
}

extern "C" void kernel_launch(void* const* d_in, const int* in_sizes, int n_in,
                              void* d_out, int out_size, void* d_ws, size_t ws_size,
                              hipStream_t stream) {
    (void)in_sizes; (void)n_in; (void)d_ws; (void)ws_size; (void)out_size;
    const float* q = (const float*)d_in[0];
    const float* k = (const float*)d_in[1];
    const float* v = (const float*)d_in[2];
    // d_in[3] is the mask: it is tril(L,L) by construction; gn>gm reproduces it exactly.
    float* out  = (float*)d_out;
    float* attn = (float*)d_out + (size_t)8 * 16 * 1024 * 64;   // outputs concatenated (out, attn)
    dim3 grid(8, 128);
    sdpa_kernel<<<grid, dim3(256), 0, stream>>>(q, k, v, out, attn);
}

// Round 4
// 716.477 us; speedup vs baseline: 1.5000x; 1.0931x over previous
//
#include <hip/hip_runtime.h>

#define L_  1024
#define D_  64
#define TM  128
#define TN  64
#define LDK 72            // padded ushort stride (64 + 8) -> 144 B rows, 16B-aligned
#define NT  (L_ / TN)

typedef __attribute__((ext_vector_type(8))) short          short8;
typedef __attribute__((ext_vector_type(8))) unsigned short ushort8;
typedef __attribute__((ext_vector_type(4))) float          f32x4;

__device__ __forceinline__ unsigned short bf16r(float f) {
    unsigned u = __builtin_bit_cast(unsigned, f);
    u += 0x7fffu + ((u >> 16) & 1u);          // round-to-nearest-even
    return (unsigned short)(u >> 16);
}

__global__ __launch_bounds__(256, 2)
void sdpa_kernel(const float* __restrict__ q, const float* __restrict__ kmat,
                 const float* __restrict__ v, float* __restrict__ out,
                 float* __restrict__ attn)
{
    __shared__ __align__(16) unsigned short Qs[TM * LDK];   // Q[m][k]   bf16
    __shared__ __align__(16) unsigned short Ks[TN * LDK];   // Kt^T[n][k] bf16 (n-major)
    __shared__ __align__(16) unsigned short Vs[D_ * LDK];   // V^T[c][n'] bf16 (c-major)
    __shared__ __align__(16) unsigned short Ps[TM * LDK];   // P[m][n']  bf16

    const int t    = threadIdx.x;
    const int wave = t >> 6;
    const int lane = t & 63;
    const int quad = lane >> 4;
    const int l15  = lane & 15;
    // XCD-aware mapping: grid(128, 8); linear = bh + 128*rt -> XCD = bh % 8.
    // All 8 row-tile blocks of one (b,h) share one XCD's 4MB L2 (K/V panels ~768KB).
    const int bh   = blockIdx.x;          // 0..127
    const int rt   = blockIdx.y;          // row tile 0..7
    const int m0   = rt * TM;
    const int rowA = wave * 32;           // this wave's rows within tile

    const float* qb = q    + (size_t)bh * (L_ * D_);
    const float* kb = kmat + (size_t)bh * (L_ * D_);   // Kt[kk][n] at kk*1024+n (reshape!)
    const float* vb = v    + (size_t)bh * (L_ * D_);
    float* outb  = out  + (size_t)bh * (L_ * D_);
    float* attnb = attn + (size_t)bh * ((size_t)L_ * L_);

    // ---- stage Q tile (once): coalesced float4, cvt bf16 ----
    #pragma unroll
    for (int i = 0; i < 8; ++i) {
        int idx = (i * 256 + t) * 4;            // 0..8191
        int m = idx >> 6, c = idx & 63;
        float4 f = *(const float4*)&qb[(size_t)(m0 + m) * D_ + c];
        ushort4 b;
        b.x = bf16r(f.x); b.y = bf16r(f.y); b.z = bf16r(f.z); b.w = bf16r(f.w);
        *(ushort4*)&Qs[m * LDK + c] = b;
    }

    // ---- staging lambdas (micro-transpose 8k x 2n per thread) ----
    auto stageK = [&](int nt) {
        const int ng = t & 31, kg = t >> 5;     // n = 2*ng, kk0 = 8*kg
        const float* src = kb + (size_t)(kg * 8) * L_ + nt * TN + 2 * ng;
        float2 a[8];
        #pragma unroll
        for (int j = 0; j < 8; ++j) a[j] = *(const float2*)(src + (size_t)j * L_);
        ushort8 r0, r1;
        #pragma unroll
        for (int j = 0; j < 8; ++j) { r0[j] = bf16r(a[j].x); r1[j] = bf16r(a[j].y); }
        *(ushort8*)&Ks[(2 * ng)     * LDK + kg * 8] = r0;
        *(ushort8*)&Ks[(2 * ng + 1) * LDK + kg * 8] = r1;
    };
    auto stageV = [&](int nt) {
        const int cg = t & 31, ngp = t >> 5;    // c = 2*cg, n0 = 8*ngp
        const float* src = vb + (size_t)(nt * TN + ngp * 8) * D_ + 2 * cg;
        float2 a[8];
        #pragma unroll
        for (int j = 0; j < 8; ++j) a[j] = *(const float2*)(src + (size_t)j * D_);
        ushort8 r0, r1;
        #pragma unroll
        for (int j = 0; j < 8; ++j) { r0[j] = bf16r(a[j].x); r1[j] = bf16r(a[j].y); }
        *(ushort8*)&Vs[(2 * cg)     * LDK + ngp * 8] = r0;
        *(ushort8*)&Vs[(2 * cg + 1) * LDK + ngp * 8] = r1;
    };

    // Transposed score: acc[tr][tc] = S^T tile -> lane holds row m = (tr*16+l15),
    // cols n = tc*16 + quad*4 + r. Same LDS reads as before; operands SWAPPED.
    auto computeScoreT = [&](f32x4 (&acc)[2][4]) {
        #pragma unroll
        for (int ks = 0; ks < 2; ++ks) {
            const int cu = ks * 32 + quad * 8;
            short8 af[2];
            #pragma unroll
            for (int tr = 0; tr < 2; ++tr)
                af[tr] = *(const short8*)&Qs[(rowA + tr * 16 + l15) * LDK + cu];
            #pragma unroll
            for (int tc = 0; tc < 4; ++tc) {
                short8 bfr = *(const short8*)&Ks[(tc * 16 + l15) * LDK + cu];
                #pragma unroll
                for (int tr = 0; tr < 2; ++tr)
                    acc[tr][tc] = __builtin_amdgcn_mfma_f32_16x16x32_bf16(bfr, af[tr], acc[tr][tc], 0, 0, 0);
            }
        }
    };

    const f32x4 zero4 = {0.f, 0.f, 0.f, 0.f};

    // ================= Phase 1: row sums Z (triangular sweep) =================
    // zpart[tr][tc]: 4 independent accumulation chains per row (depth 4 per tile)
    float zpart[2][4] = {};
    const int ntmax1 = (m0 + TM - 1) / TN;      // last tile touching the diagonal
    __syncthreads();                            // Qs visible
    for (int nt = 0; nt <= ntmax1; ++nt) {
        stageK(nt);
        __syncthreads();
        f32x4 acc[2][4];
        #pragma unroll
        for (int tr = 0; tr < 2; ++tr)
            #pragma unroll
            for (int tc = 0; tc < 4; ++tc) acc[tr][tc] = zero4;
        computeScoreT(acc);
        #pragma unroll
        for (int tr = 0; tr < 2; ++tr) {
            const int gm = m0 + rowA + tr * 16 + l15;
            #pragma unroll
            for (int tc = 0; tc < 4; ++tc)
                #pragma unroll
                for (int r = 0; r < 4; ++r) {
                    const int gn = nt * TN + tc * 16 + quad * 4 + r;
                    zpart[tr][tc] += (gn > gm) ? 1.0f : __expf(acc[tr][tc][r] * 0.125f);
                }
        }
        __syncthreads();                        // protect Ks before next stage
    }
    // Masked columns in tiles nt > ntmax1 never visited above: each contributes
    // exp(-1e-12) == 1.0f to the softmax denominator. Block-uniform count.
    const float zmissing = (float)(L_ - (ntmax1 + 1) * TN);
    float rcpz[2];
    #pragma unroll
    for (int tr = 0; tr < 2; ++tr) {
        float z = (zpart[tr][0] + zpart[tr][1]) + (zpart[tr][2] + zpart[tr][3]);
        z += __shfl_xor(z, 16);                 // sum across quads (same l15)
        z += __shfl_xor(z, 32);
        rcpz[tr] = 1.0f / (z + zmissing);
    }

    // ================= Phase 2: write attn, accumulate out = P @ V =================
    f32x4 oacc[2][4];
    #pragma unroll
    for (int tr = 0; tr < 2; ++tr)
        #pragma unroll
        for (int tc = 0; tc < 4; ++tc) oacc[tr][tc] = zero4;

    for (int nt = 0; nt < NT; ++nt) {
        const bool fullmask = (nt * TN) > (m0 + TM - 1);   // block-uniform
        __syncthreads();                                   // prev iter done with Ks/Vs/Ps
        if (!fullmask) stageK(nt);
        stageV(nt);
        __syncthreads();

        if (!fullmask) {
            f32x4 acc[2][4];
            #pragma unroll
            for (int tr = 0; tr < 2; ++tr)
                #pragma unroll
                for (int tc = 0; tc < 4; ++tc) acc[tr][tc] = zero4;
            computeScoreT(acc);
            #pragma unroll
            for (int tr = 0; tr < 2; ++tr) {
                const int lrow = rowA + tr * 16 + l15;
                const int gm = m0 + lrow;
                const float rz = rcpz[tr];
                #pragma unroll
                for (int tc = 0; tc < 4; ++tc) {
                    float p[4];
                    #pragma unroll
                    for (int r = 0; r < 4; ++r) {
                        const int gn = nt * TN + tc * 16 + quad * 4 + r;
                        float e = (gn > gm) ? 1.0f : __expf(acc[tr][tc][r] * 0.125f);
                        p[r] = e * rz;
                    }
                    float4 vv = {p[0], p[1], p[2], p[3]};
                    *(float4*)&attnb[(size_t)gm * L_ + nt * TN + tc * 16 + quad * 4] = vv;
                    ushort4 pw;
                    pw.x = bf16r(p[0]); pw.y = bf16r(p[1]);
                    pw.z = bf16r(p[2]); pw.w = bf16r(p[3]);
                    *(ushort4*)&Ps[lrow * LDK + tc * 16 + quad * 4] = pw;
                }
            }
        } else {
            // row-constant value 1/Z: broadcast stores; Ps content is nt-invariant
            const bool firstFull = (nt == ntmax1 + 1);
            #pragma unroll
            for (int tr = 0; tr < 2; ++tr) {
                const int lrow = rowA + tr * 16 + l15;
                const int gm = m0 + lrow;
                const float rz = rcpz[tr];
                float4 vv = {rz, rz, rz, rz};
                const unsigned short pb = bf16r(rz);
                ushort4 p4; p4.x = pb; p4.y = pb; p4.z = pb; p4.w = pb;
                #pragma unroll
                for (int c = 0; c < 4; ++c) {
                    *(float4*)&attnb[(size_t)gm * L_ + nt * TN + c * 16 + quad * 4] = vv;
                    if (firstFull)
                        *(ushort4*)&Ps[lrow * LDK + c * 16 + quad * 4] = p4;
                }
            }
        }
        __syncthreads();                                   // Ps ready

        #pragma unroll
        for (int ks = 0; ks < 2; ++ks) {
            const int cu = ks * 32 + quad * 8;
            short8 pf[2];
            #pragma unroll
            for (int tr = 0; tr < 2; ++tr)
                pf[tr] = *(const short8*)&Ps[(rowA + tr * 16 + l15) * LDK + cu];
            #pragma unroll
            for (int tc = 0; tc < 4; ++tc) {
                short8 vf = *(const short8*)&Vs[(tc * 16 + l15) * LDK + cu];
                #pragma unroll
                for (int tr = 0; tr < 2; ++tr)
                    oacc[tr][tc] = __builtin_amdgcn_mfma_f32_16x16x32_bf16(pf[tr], vf, oacc[tr][tc], 0, 0, 0);
            }
        }
    }

    // epilogue: store out (already normalized)
    #pragma unroll
    for (int tr = 0; tr < 2; ++tr)
        #pragma unroll
        for (int r = 0; r < 4; ++r) {
            const int gm = m0 + rowA + tr * 16 + quad * 4 + r;
            #pragma unroll
            for (int tc = 0; tc < 4; ++tc)
                outb[(size_t)gm * D_ + tc * 16 + l15] = oacc[tr][tc][r];
        }
}

extern "C" void kernel_launch(void* const* d_in, const int* in_sizes, int n_in,
                              void* d_out, int out_size, void* d_ws, size_t ws_size,
                              hipStream_t stream) {
    (void)in_sizes; (void)n_in; (void)d_ws; (void)ws_size; (void)out_size;
    const float* q = (const float*)d_in[0];
    const float* k = (const float*)d_in[1];
    const float* v = (const float*)d_in[2];
    // d_in[3] is the mask: it is tril(L,L) by construction; gn>gm reproduces it exactly.
    float* out  = (float*)d_out;
    float* attn = (float*)d_out + (size_t)8 * 16 * 1024 * 64;   // outputs concatenated (out, attn)
    dim3 grid(128, 8);   // x = bh (XCD = bh%8), y = rt
    sdpa_kernel<<<grid, dim3(256), 0, stream>>>(q, k, v, out, attn);
}

// Round 5
// 714.940 us; speedup vs baseline: 1.5033x; 1.0021x over previous
//
#include <hip/hip_runtime.h>

#define L_  1024
#define D_  64
#define TM  128
#define TN  64
#define LDK 72            // padded ushort stride (64 + 8) -> 144 B rows, 16B-aligned
#define NT  (L_ / TN)

typedef __attribute__((ext_vector_type(8))) short          short8;
typedef __attribute__((ext_vector_type(8))) unsigned short ushort8;
typedef __attribute__((ext_vector_type(4))) float          f32x4;

__device__ __forceinline__ unsigned short bf16r(float f) {
    unsigned u = __builtin_bit_cast(unsigned, f);
    u += 0x7fffu + ((u >> 16) & 1u);          // round-to-nearest-even
    return (unsigned short)(u >> 16);
}

__global__ __launch_bounds__(256, 2)
void sdpa_kernel(const float* __restrict__ q, const float* __restrict__ kmat,
                 const float* __restrict__ v, float* __restrict__ out,
                 float* __restrict__ attn)
{
    __shared__ __align__(16) unsigned short Qs[TM * LDK];      // Q[m][k]    bf16
    __shared__ __align__(16) unsigned short Ks[2][TN * LDK];   // Kt^T[n][k] bf16, double-buffered
    __shared__ __align__(16) unsigned short Vs[2][D_ * LDK];   // V^T[c][n'] bf16, double-buffered
    __shared__ __align__(16) unsigned short Ps[TM * LDK];      // P[m][n']   bf16 (wave-local rows)
    // total 72 KB -> 2 blocks/CU (144/160 KB)

    const int t    = threadIdx.x;
    const int wave = t >> 6;
    const int lane = t & 63;
    const int quad = lane >> 4;
    const int l15  = lane & 15;
    // XCD-aware mapping: grid(128, 8); linear = bh + 128*rt -> XCD = bh % 8.
    const int bh   = blockIdx.x;          // 0..127
    const int rt   = blockIdx.y;          // row tile 0..7
    const int m0   = rt * TM;
    const int rowA = wave * 32;           // this wave's rows within tile

    const float* qb = q    + (size_t)bh * (L_ * D_);
    const float* kb = kmat + (size_t)bh * (L_ * D_);   // Kt[kk][n] at kk*1024+n (reshape!)
    const float* vb = v    + (size_t)bh * (L_ * D_);
    float* outb  = out  + (size_t)bh * (L_ * D_);
    float* attnb = attn + (size_t)bh * ((size_t)L_ * L_);

    // ---- stage Q tile (once): coalesced float4, cvt bf16 ----
    #pragma unroll
    for (int i = 0; i < 8; ++i) {
        int idx = (i * 256 + t) * 4;            // 0..8191
        int m = idx >> 6, c = idx & 63;
        float4 f = *(const float4*)&qb[(size_t)(m0 + m) * D_ + c];
        ushort4 b;
        b.x = bf16r(f.x); b.y = bf16r(f.y); b.z = bf16r(f.z); b.w = bf16r(f.w);
        *(ushort4*)&Qs[m * LDK + c] = b;
    }

    // ---- reg-staged double-buffer staging (issue-early / LDS-write-late) ----
    const int ng = t & 31, kg = t >> 5;   // shared decomposition for K and V
    float2 rK[8], rV[8];

    auto loadK = [&](int nt) {            // K tile nt -> rK (global issue)
        const float* src = kb + (size_t)(kg * 8) * L_ + nt * TN + 2 * ng;
        #pragma unroll
        for (int j = 0; j < 8; ++j) rK[j] = *(const float2*)(src + (size_t)j * L_);
    };
    auto writeK = [&](unsigned short* dst) {   // rK -> LDS (waits vmcnt here)
        ushort8 r0, r1;
        #pragma unroll
        for (int j = 0; j < 8; ++j) { r0[j] = bf16r(rK[j].x); r1[j] = bf16r(rK[j].y); }
        *(ushort8*)&dst[(2 * ng)     * LDK + kg * 8] = r0;
        *(ushort8*)&dst[(2 * ng + 1) * LDK + kg * 8] = r1;
    };
    auto loadV = [&](int nt) {            // V tile nt -> rV
        const float* src = vb + (size_t)(nt * TN + kg * 8) * D_ + 2 * ng;
        #pragma unroll
        for (int j = 0; j < 8; ++j) rV[j] = *(const float2*)(src + (size_t)j * D_);
    };
    auto writeV = [&](unsigned short* dst) {
        ushort8 r0, r1;
        #pragma unroll
        for (int j = 0; j < 8; ++j) { r0[j] = bf16r(rV[j].x); r1[j] = bf16r(rV[j].y); }
        *(ushort8*)&dst[(2 * ng)     * LDK + kg * 8] = r0;
        *(ushort8*)&dst[(2 * ng + 1) * LDK + kg * 8] = r1;
    };

    // Transposed score: lane holds row m = (tr*16+l15), cols n = tc*16+quad*4+r.
    auto computeScoreT = [&](f32x4 (&acc)[2][4], const unsigned short* ksrc) {
        #pragma unroll
        for (int ks = 0; ks < 2; ++ks) {
            const int cu = ks * 32 + quad * 8;
            short8 af[2];
            #pragma unroll
            for (int tr = 0; tr < 2; ++tr)
                af[tr] = *(const short8*)&Qs[(rowA + tr * 16 + l15) * LDK + cu];
            #pragma unroll
            for (int tc = 0; tc < 4; ++tc) {
                short8 bfr = *(const short8*)&ksrc[(tc * 16 + l15) * LDK + cu];
                #pragma unroll
                for (int tr = 0; tr < 2; ++tr)
                    acc[tr][tc] = __builtin_amdgcn_mfma_f32_16x16x32_bf16(bfr, af[tr], acc[tr][tc], 0, 0, 0);
            }
        }
    };

    const f32x4 zero4 = {0.f, 0.f, 0.f, 0.f};

    // ================= Phase 1: row sums Z (triangular sweep) =================
    float zpart[2][4] = {};
    const int ntmax1 = (m0 + TM - 1) / TN;      // last tile touching the diagonal
    loadK(0); writeK(Ks[0]);                    // prologue stage (visible at first barrier)
    for (int nt = 0; nt <= ntmax1; ++nt) {
        __syncthreads();                        // Ks[nt&1] (and Qs at nt=0) visible;
                                                // all waves done reading Ks[(nt+1)&1]
        if (nt < ntmax1) loadK(nt + 1);         // in flight during compute below
        f32x4 acc[2][4];
        #pragma unroll
        for (int tr = 0; tr < 2; ++tr)
            #pragma unroll
            for (int tc = 0; tc < 4; ++tc) acc[tr][tc] = zero4;
        computeScoreT(acc, Ks[nt & 1]);
        #pragma unroll
        for (int tr = 0; tr < 2; ++tr) {
            const int gm = m0 + rowA + tr * 16 + l15;
            #pragma unroll
            for (int tc = 0; tc < 4; ++tc)
                #pragma unroll
                for (int r = 0; r < 4; ++r) {
                    const int gn = nt * TN + tc * 16 + quad * 4 + r;
                    zpart[tr][tc] += (gn > gm) ? 1.0f : __expf(acc[tr][tc][r] * 0.125f);
                }
        }
        if (nt < ntmax1) writeK(Ks[(nt + 1) & 1]);   // consume loads at region end
    }
    // Masked columns in tiles nt > ntmax1: each contributes exp(-1e-12) == 1.0f.
    const float zmissing = (float)(L_ - (ntmax1 + 1) * TN);

    loadK(0); loadV(0);                          // phase-2 prologue issue (overlaps rcpz)
    float rcpz[2];
    #pragma unroll
    for (int tr = 0; tr < 2; ++tr) {
        float z = (zpart[tr][0] + zpart[tr][1]) + (zpart[tr][2] + zpart[tr][3]);
        z += __shfl_xor(z, 16);                 // sum across quads (same l15)
        z += __shfl_xor(z, 32);
        rcpz[tr] = 1.0f / (z + zmissing);
    }
    __syncthreads();                            // all phase-1 reads of Ks done
    writeK(Ks[0]); writeV(Vs[0]);

    // ================= Phase 2: write attn, accumulate out = P @ V =================
    f32x4 oacc[2][4];
    #pragma unroll
    for (int tr = 0; tr < 2; ++tr)
        #pragma unroll
        for (int tc = 0; tc < 4; ++tc) oacc[tr][tc] = zero4;

    for (int nt = 0; nt < NT; ++nt) {
        const bool fullmask = (nt * TN) > (m0 + TM - 1);   // block-uniform
        __syncthreads();                        // bufs[nt&1] visible; prev reads of bufs[(nt+1)&1] done
        const int nn = nt + 1;
        const bool nextV = (nn < NT);
        const bool nextK = nextV && ((nn * TN) <= (m0 + TM - 1));
        if (nextV) loadV(nn);                   // in flight during everything below
        if (nextK) loadK(nn);

        if (!fullmask) {
            f32x4 acc[2][4];
            #pragma unroll
            for (int tr = 0; tr < 2; ++tr)
                #pragma unroll
                for (int tc = 0; tc < 4; ++tc) acc[tr][tc] = zero4;
            computeScoreT(acc, Ks[nt & 1]);
            #pragma unroll
            for (int tr = 0; tr < 2; ++tr) {
                const int lrow = rowA + tr * 16 + l15;
                const int gm = m0 + lrow;
                const float rz = rcpz[tr];
                #pragma unroll
                for (int tc = 0; tc < 4; ++tc) {
                    float p[4];
                    #pragma unroll
                    for (int r = 0; r < 4; ++r) {
                        const int gn = nt * TN + tc * 16 + quad * 4 + r;
                        float e = (gn > gm) ? 1.0f : __expf(acc[tr][tc][r] * 0.125f);
                        p[r] = e * rz;
                    }
                    float4 vv = {p[0], p[1], p[2], p[3]};
                    *(float4*)&attnb[(size_t)gm * L_ + nt * TN + tc * 16 + quad * 4] = vv;
                    ushort4 pw;
                    pw.x = bf16r(p[0]); pw.y = bf16r(p[1]);
                    pw.z = bf16r(p[2]); pw.w = bf16r(p[3]);
                    *(ushort4*)&Ps[lrow * LDK + tc * 16 + quad * 4] = pw;
                }
            }
        } else {
            // row-constant value 1/Z: broadcast stores; Ps content is nt-invariant
            const bool firstFull = (nt == ntmax1 + 1);
            #pragma unroll
            for (int tr = 0; tr < 2; ++tr) {
                const int lrow = rowA + tr * 16 + l15;
                const int gm = m0 + lrow;
                const float rz = rcpz[tr];
                float4 vv = {rz, rz, rz, rz};
                const unsigned short pb = bf16r(rz);
                ushort4 p4; p4.x = pb; p4.y = pb; p4.z = pb; p4.w = pb;
                #pragma unroll
                for (int c = 0; c < 4; ++c) {
                    *(float4*)&attnb[(size_t)gm * L_ + nt * TN + c * 16 + quad * 4] = vv;
                    if (firstFull)
                        *(ushort4*)&Ps[lrow * LDK + c * 16 + quad * 4] = p4;
                }
            }
        }

        // NO barrier: PV's pf reads only THIS wave's 32 Ps rows (per-wave LDS
        // ordering suffices); vf reads Vs[nt&1], covered by the top barrier.
        #pragma unroll
        for (int ks = 0; ks < 2; ++ks) {
            const int cu = ks * 32 + quad * 8;
            short8 pf[2];
            #pragma unroll
            for (int tr = 0; tr < 2; ++tr)
                pf[tr] = *(const short8*)&Ps[(rowA + tr * 16 + l15) * LDK + cu];
            #pragma unroll
            for (int tc = 0; tc < 4; ++tc) {
                short8 vf = *(const short8*)&Vs[nt & 1][(tc * 16 + l15) * LDK + cu];
                #pragma unroll
                for (int tr = 0; tr < 2; ++tr)
                    oacc[tr][tc] = __builtin_amdgcn_mfma_f32_16x16x32_bf16(pf[tr], vf, oacc[tr][tc], 0, 0, 0);
            }
        }

        if (nextV) writeV(Vs[nn & 1]);          // consume in-flight loads at region end
        if (nextK) writeK(Ks[nn & 1]);
    }

    // epilogue: store out (already normalized)
    #pragma unroll
    for (int tr = 0; tr < 2; ++tr)
        #pragma unroll
        for (int r = 0; r < 4; ++r) {
            const int gm = m0 + rowA + tr * 16 + quad * 4 + r;
            #pragma unroll
            for (int tc = 0; tc < 4; ++tc)
                outb[(size_t)gm * D_ + tc * 16 + l15] = oacc[tr][tc][r];
        }
}

extern "C" void kernel_launch(void* const* d_in, const int* in_sizes, int n_in,
                              void* d_out, int out_size, void* d_ws, size_t ws_size,
                              hipStream_t stream) {
    (void)in_sizes; (void)n_in; (void)d_ws; (void)ws_size; (void)out_size;
    const float* q = (const float*)d_in[0];
    const float* k = (const float*)d_in[1];
    const float* v = (const float*)d_in[2];
    // d_in[3] is the mask: it is tril(L,L) by construction; gn>gm reproduces it exactly.
    float* out  = (float*)d_out;
    float* attn = (float*)d_out + (size_t)8 * 16 * 1024 * 64;   // outputs concatenated (out, attn)
    dim3 grid(128, 8);   // x = bh (XCD = bh%8), y = rt
    sdpa_kernel<<<grid, dim3(256), 0, stream>>>(q, k, v, out, attn);
}

// Round 6
// 711.982 us; speedup vs baseline: 1.5095x; 1.0042x over previous
//
#include <hip/hip_runtime.h>

#define L_  1024
#define D_  64
#define TM  128
#define TN  64
#define LDK 72            // padded ushort stride (64 + 8) -> 144 B rows, 16B-aligned
#define NT  (L_ / TN)

typedef __attribute__((ext_vector_type(8))) short          short8;
typedef __attribute__((ext_vector_type(8))) unsigned short ushort8;
typedef __attribute__((ext_vector_type(4))) float          f32x4;

__device__ __forceinline__ unsigned short bf16r(float f) {
    unsigned u = __builtin_bit_cast(unsigned, f);
    u += 0x7fffu + ((u >> 16) & 1u);          // round-to-nearest-even
    return (unsigned short)(u >> 16);
}

// LDS-only barrier: orders ds ops across waves WITHOUT draining vmcnt.
// __syncthreads would emit s_waitcnt vmcnt(0) lgkmcnt(0) and stall every wave
// on its in-flight attn stores each tile; here stores stay in flight.
__device__ __forceinline__ void barrier_lds() {
    asm volatile("s_waitcnt lgkmcnt(0)" ::: "memory");
    __builtin_amdgcn_s_barrier();
}

__global__ __launch_bounds__(256, 2)
void sdpa_kernel(const float* __restrict__ q, const float* __restrict__ kmat,
                 const float* __restrict__ v, float* __restrict__ out,
                 float* __restrict__ attn)
{
    __shared__ __align__(16) unsigned short Qs[TM * LDK];      // Q[m][k]    bf16
    __shared__ __align__(16) unsigned short Ks[2][TN * LDK];   // Kt^T[n][k] bf16, double-buffered
    __shared__ __align__(16) unsigned short Vs[2][D_ * LDK];   // V^T[c][n'] bf16, double-buffered
    __shared__ __align__(16) unsigned short Ps[TM * LDK];      // P[m][n']   bf16 (wave-local rows)
    // total 72 KB -> 2 blocks/CU (144/160 KB)

    const int t    = threadIdx.x;
    const int wave = t >> 6;
    const int lane = t & 63;
    const int quad = lane >> 4;
    const int l15  = lane & 15;
    // XCD-aware mapping: grid(128, 8); linear = bh + 128*rt -> XCD = bh % 8.
    const int bh   = blockIdx.x;          // 0..127
    const int rt   = blockIdx.y;          // row tile 0..7
    const int m0   = rt * TM;
    const int rowA = wave * 32;           // this wave's rows within tile

    const float* qb = q    + (size_t)bh * (L_ * D_);
    const float* kb = kmat + (size_t)bh * (L_ * D_);   // Kt[kk][n] at kk*1024+n (reshape!)
    const float* vb = v    + (size_t)bh * (L_ * D_);
    float* outb  = out  + (size_t)bh * (L_ * D_);
    float* attnb = attn + (size_t)bh * ((size_t)L_ * L_);

    // ---- stage Q tile (once): coalesced float4, cvt bf16 ----
    #pragma unroll
    for (int i = 0; i < 8; ++i) {
        int idx = (i * 256 + t) * 4;            // 0..8191
        int m = idx >> 6, c = idx & 63;
        float4 f = *(const float4*)&qb[(size_t)(m0 + m) * D_ + c];
        ushort4 b;
        b.x = bf16r(f.x); b.y = bf16r(f.y); b.z = bf16r(f.z); b.w = bf16r(f.w);
        *(ushort4*)&Qs[m * LDK + c] = b;
    }

    // ---- reg-staged double-buffer staging (issue-early / LDS-write-late) ----
    const int ng = t & 31, kg = t >> 5;   // shared decomposition for K and V
    float2 rK[8], rV[8];

    auto loadK = [&](int nt) {            // K tile nt -> rK (global issue)
        const float* src = kb + (size_t)(kg * 8) * L_ + nt * TN + 2 * ng;
        #pragma unroll
        for (int j = 0; j < 8; ++j) rK[j] = *(const float2*)(src + (size_t)j * L_);
    };
    auto writeK = [&](unsigned short* dst) {   // rK -> LDS (compiler waits vmcnt for rK here)
        ushort8 r0, r1;
        #pragma unroll
        for (int j = 0; j < 8; ++j) { r0[j] = bf16r(rK[j].x); r1[j] = bf16r(rK[j].y); }
        *(ushort8*)&dst[(2 * ng)     * LDK + kg * 8] = r0;
        *(ushort8*)&dst[(2 * ng + 1) * LDK + kg * 8] = r1;
    };
    auto loadV = [&](int nt) {            // V tile nt -> rV
        const float* src = vb + (size_t)(nt * TN + kg * 8) * D_ + 2 * ng;
        #pragma unroll
        for (int j = 0; j < 8; ++j) rV[j] = *(const float2*)(src + (size_t)j * D_);
    };
    auto writeV = [&](unsigned short* dst) {
        ushort8 r0, r1;
        #pragma unroll
        for (int j = 0; j < 8; ++j) { r0[j] = bf16r(rV[j].x); r1[j] = bf16r(rV[j].y); }
        *(ushort8*)&dst[(2 * ng)     * LDK + kg * 8] = r0;
        *(ushort8*)&dst[(2 * ng + 1) * LDK + kg * 8] = r1;
    };

    // Transposed score: lane holds row m = (tr*16+l15), cols n = tc*16+quad*4+r.
    auto computeScoreT = [&](f32x4 (&acc)[2][4], const unsigned short* ksrc) {
        #pragma unroll
        for (int ks = 0; ks < 2; ++ks) {
            const int cu = ks * 32 + quad * 8;
            short8 af[2];
            #pragma unroll
            for (int tr = 0; tr < 2; ++tr)
                af[tr] = *(const short8*)&Qs[(rowA + tr * 16 + l15) * LDK + cu];
            #pragma unroll
            for (int tc = 0; tc < 4; ++tc) {
                short8 bfr = *(const short8*)&ksrc[(tc * 16 + l15) * LDK + cu];
                #pragma unroll
                for (int tr = 0; tr < 2; ++tr)
                    acc[tr][tc] = __builtin_amdgcn_mfma_f32_16x16x32_bf16(bfr, af[tr], acc[tr][tc], 0, 0, 0);
            }
        }
    };

    const f32x4 zero4 = {0.f, 0.f, 0.f, 0.f};

    // ================= Phase 1: row sums Z (triangular sweep) =================
    float zpart[2][4] = {};
    const int ntmax1 = (m0 + TM - 1) / TN;      // last tile touching the diagonal
    loadK(0); writeK(Ks[0]);                    // prologue stage (visible at first barrier)
    for (int nt = 0; nt <= ntmax1; ++nt) {
        barrier_lds();                          // Ks[nt&1] (and Qs at nt=0) visible;
                                                // all waves done reading Ks[(nt+1)&1].
                                                // NO vmcnt drain: attn/K stores fly free.
        if (nt < ntmax1) loadK(nt + 1);         // in flight during compute below
        f32x4 acc[2][4];
        #pragma unroll
        for (int tr = 0; tr < 2; ++tr)
            #pragma unroll
            for (int tc = 0; tc < 4; ++tc) acc[tr][tc] = zero4;
        computeScoreT(acc, Ks[nt & 1]);
        #pragma unroll
        for (int tr = 0; tr < 2; ++tr) {
            const int gm = m0 + rowA + tr * 16 + l15;
            #pragma unroll
            for (int tc = 0; tc < 4; ++tc)
                #pragma unroll
                for (int r = 0; r < 4; ++r) {
                    const int gn = nt * TN + tc * 16 + quad * 4 + r;
                    zpart[tr][tc] += (gn > gm) ? 1.0f : __expf(acc[tr][tc][r] * 0.125f);
                }
        }
        if (nt < ntmax1) writeK(Ks[(nt + 1) & 1]);   // consume loads at region end
    }
    // Masked columns in tiles nt > ntmax1: each contributes exp(-1e-12) == 1.0f.
    const float zmissing = (float)(L_ - (ntmax1 + 1) * TN);

    loadK(0); loadV(0);                          // phase-2 prologue issue (overlaps rcpz)
    float rcpz[2];
    #pragma unroll
    for (int tr = 0; tr < 2; ++tr) {
        float z = (zpart[tr][0] + zpart[tr][1]) + (zpart[tr][2] + zpart[tr][3]);
        z += __shfl_xor(z, 16);                 // sum across quads (same l15)
        z += __shfl_xor(z, 32);
        rcpz[tr] = 1.0f / (z + zmissing);
    }
    __syncthreads();                            // all phase-1 reads of Ks done (cold, once)
    writeK(Ks[0]); writeV(Vs[0]);

    // ================= Phase 2: write attn, accumulate out = P @ V =================
    f32x4 oacc[2][4];
    #pragma unroll
    for (int tr = 0; tr < 2; ++tr)
        #pragma unroll
        for (int tc = 0; tc < 4; ++tc) oacc[tr][tc] = zero4;

    for (int nt = 0; nt < NT; ++nt) {
        const bool fullmask = (nt * TN) > (m0 + TM - 1);   // block-uniform
        barrier_lds();                          // bufs[nt&1] visible; prev reads of
                                                // bufs[(nt+1)&1] done. No vmcnt drain.
        const int nn = nt + 1;
        const bool nextV = (nn < NT);
        const bool nextK = nextV && ((nn * TN) <= (m0 + TM - 1));
        if (nextV) loadV(nn);                   // in flight during everything below
        if (nextK) loadK(nn);

        if (!fullmask) {
            f32x4 acc[2][4];
            #pragma unroll
            for (int tr = 0; tr < 2; ++tr)
                #pragma unroll
                for (int tc = 0; tc < 4; ++tc) acc[tr][tc] = zero4;
            computeScoreT(acc, Ks[nt & 1]);
            #pragma unroll
            for (int tr = 0; tr < 2; ++tr) {
                const int lrow = rowA + tr * 16 + l15;
                const int gm = m0 + lrow;
                const float rz = rcpz[tr];
                #pragma unroll
                for (int tc = 0; tc < 4; ++tc) {
                    float p[4];
                    #pragma unroll
                    for (int r = 0; r < 4; ++r) {
                        const int gn = nt * TN + tc * 16 + quad * 4 + r;
                        float e = (gn > gm) ? 1.0f : __expf(acc[tr][tc][r] * 0.125f);
                        p[r] = e * rz;
                    }
                    float4 vv = {p[0], p[1], p[2], p[3]};
                    *(float4*)&attnb[(size_t)gm * L_ + nt * TN + tc * 16 + quad * 4] = vv;
                    ushort4 pw;
                    pw.x = bf16r(p[0]); pw.y = bf16r(p[1]);
                    pw.z = bf16r(p[2]); pw.w = bf16r(p[3]);
                    *(ushort4*)&Ps[lrow * LDK + tc * 16 + quad * 4] = pw;
                }
            }
        } else {
            // row-constant value 1/Z: broadcast stores; Ps content is nt-invariant
            const bool firstFull = (nt == ntmax1 + 1);
            #pragma unroll
            for (int tr = 0; tr < 2; ++tr) {
                const int lrow = rowA + tr * 16 + l15;
                const int gm = m0 + lrow;
                const float rz = rcpz[tr];
                float4 vv = {rz, rz, rz, rz};
                const unsigned short pb = bf16r(rz);
                ushort4 p4; p4.x = pb; p4.y = pb; p4.z = pb; p4.w = pb;
                #pragma unroll
                for (int c = 0; c < 4; ++c) {
                    *(float4*)&attnb[(size_t)gm * L_ + nt * TN + c * 16 + quad * 4] = vv;
                    if (firstFull)
                        *(ushort4*)&Ps[lrow * LDK + c * 16 + quad * 4] = p4;
                }
            }
        }

        // NO barrier: PV's pf reads only THIS wave's 32 Ps rows (compiler tracks
        // the same-wave Ps RAW through lgkmcnt); vf reads Vs[nt&1] (top barrier).
        #pragma unroll
        for (int ks = 0; ks < 2; ++ks) {
            const int cu = ks * 32 + quad * 8;
            short8 pf[2];
            #pragma unroll
            for (int tr = 0; tr < 2; ++tr)
                pf[tr] = *(const short8*)&Ps[(rowA + tr * 16 + l15) * LDK + cu];
            #pragma unroll
            for (int tc = 0; tc < 4; ++tc) {
                short8 vf = *(const short8*)&Vs[nt & 1][(tc * 16 + l15) * LDK + cu];
                #pragma unroll
                for (int tr = 0; tr < 2; ++tr)
                    oacc[tr][tc] = __builtin_amdgcn_mfma_f32_16x16x32_bf16(pf[tr], vf, oacc[tr][tc], 0, 0, 0);
            }
        }

        if (nextV) writeV(Vs[nn & 1]);          // consume in-flight loads at region end
        if (nextK) writeK(Ks[nn & 1]);
    }

    // epilogue: store out (already normalized)
    #pragma unroll
    for (int tr = 0; tr < 2; ++tr)
        #pragma unroll
        for (int r = 0; r < 4; ++r) {
            const int gm = m0 + rowA + tr * 16 + quad * 4 + r;
            #pragma unroll
            for (int tc = 0; tc < 4; ++tc)
                outb[(size_t)gm * D_ + tc * 16 + l15] = oacc[tr][tc][r];
        }
}

extern "C" void kernel_launch(void* const* d_in, const int* in_sizes, int n_in,
                              void* d_out, int out_size, void* d_ws, size_t ws_size,
                              hipStream_t stream) {
    (void)in_sizes; (void)n_in; (void)d_ws; (void)ws_size; (void)out_size;
    const float* q = (const float*)d_in[0];
    const float* k = (const float*)d_in[1];
    const float* v = (const float*)d_in[2];
    // d_in[3] is the mask: it is tril(L,L) by construction; gn>gm reproduces it exactly.
    float* out  = (float*)d_out;
    float* attn = (float*)d_out + (size_t)8 * 16 * 1024 * 64;   // outputs concatenated (out, attn)
    dim3 grid(128, 8);   // x = bh (XCD = bh%8), y = rt
    sdpa_kernel<<<grid, dim3(256), 0, stream>>>(q, k, v, out, attn);
}

// Round 7
// 697.376 us; speedup vs baseline: 1.5411x; 1.0209x over previous
//
#include <hip/hip_runtime.h>

#define L_  1024
#define D_  64
#define TM  128
#define TN  64
#define LDK 72            // padded ushort stride (64 + 8) -> 144 B rows, 16B-aligned
#define NT  (L_ / TN)

typedef __attribute__((ext_vector_type(8))) short          short8;
typedef __attribute__((ext_vector_type(8))) unsigned short ushort8;
typedef __attribute__((ext_vector_type(4))) float          f32x4;

__device__ __forceinline__ unsigned short bf16r(float f) {
    unsigned u = __builtin_bit_cast(unsigned, f);
    u += 0x7fffu + ((u >> 16) & 1u);          // round-to-nearest-even
    return (unsigned short)(u >> 16);
}

// LDS-only barrier: orders ds ops across waves WITHOUT draining vmcnt.
__device__ __forceinline__ void barrier_lds() {
    asm volatile("s_waitcnt lgkmcnt(0)" ::: "memory");
    __builtin_amdgcn_s_barrier();
}

__global__ __launch_bounds__(256, 2)
void sdpa_kernel(const float* __restrict__ q, const float* __restrict__ kmat,
                 const float* __restrict__ v, float* __restrict__ out,
                 float* __restrict__ attn)
{
    __shared__ __align__(16) unsigned short Qs[TM * LDK];      // Q[m][k]    bf16
    __shared__ __align__(16) unsigned short Ks[2][TN * LDK];   // Kt^T[n][k] bf16, double-buffered
    __shared__ __align__(16) unsigned short Vs[2][D_ * LDK];   // V^T[c][n'] bf16, double-buffered
    __shared__ __align__(16) unsigned short Ps[TM * LDK];      // P[m][n']   bf16 (wave-local rows)
    // total 72 KB -> 2 blocks/CU

    const int t    = threadIdx.x;
    const int wave = t >> 6;
    const int lane = t & 63;
    const int quad = lane >> 4;
    const int l15  = lane & 15;
    // Causal load balancing: each block does row-tiles {rty, 7-rty} sequentially.
    // Heavy work per block is then uniform (18 heavy tiles per phase for ALL blocks),
    // and grid = 512 blocks = exactly 2/CU -> single fully-resident dispatch round.
    const int bh   = blockIdx.x;          // 0..127 ; XCD = bh % 8 (L2 K/V panel share)
    const int rty  = blockIdx.y;          // 0..3

    const float* qb = q    + (size_t)bh * (L_ * D_);
    const float* kb = kmat + (size_t)bh * (L_ * D_);   // Kt[kk][n] at kk*1024+n (reshape!)
    const float* vb = v    + (size_t)bh * (L_ * D_);
    float* outb  = out  + (size_t)bh * (L_ * D_);
    float* attnb = attn + (size_t)bh * ((size_t)L_ * L_);

    // ---- reg-staged double-buffer staging (issue-early / LDS-write-late) ----
    const int ng = t & 31, kg = t >> 5;   // shared decomposition for K and V
    float2 rK[8], rV[8];

    auto loadK = [&](int nt) {            // K tile nt -> rK (global issue)
        const float* src = kb + (size_t)(kg * 8) * L_ + nt * TN + 2 * ng;
        #pragma unroll
        for (int j = 0; j < 8; ++j) rK[j] = *(const float2*)(src + (size_t)j * L_);
    };
    auto writeK = [&](unsigned short* dst) {   // rK -> LDS (compiler waits vmcnt here)
        ushort8 r0, r1;
        #pragma unroll
        for (int j = 0; j < 8; ++j) { r0[j] = bf16r(rK[j].x); r1[j] = bf16r(rK[j].y); }
        *(ushort8*)&dst[(2 * ng)     * LDK + kg * 8] = r0;
        *(ushort8*)&dst[(2 * ng + 1) * LDK + kg * 8] = r1;
    };
    auto loadV = [&](int nt) {            // V tile nt -> rV
        const float* src = vb + (size_t)(nt * TN + kg * 8) * D_ + 2 * ng;
        #pragma unroll
        for (int j = 0; j < 8; ++j) rV[j] = *(const float2*)(src + (size_t)j * D_);
    };
    auto writeV = [&](unsigned short* dst) {
        ushort8 r0, r1;
        #pragma unroll
        for (int j = 0; j < 8; ++j) { r0[j] = bf16r(rV[j].x); r1[j] = bf16r(rV[j].y); }
        *(ushort8*)&dst[(2 * ng)     * LDK + kg * 8] = r0;
        *(ushort8*)&dst[(2 * ng + 1) * LDK + kg * 8] = r1;
    };

    const int rowA = wave * 32;           // this wave's rows within tile

    // Transposed score: lane holds row m = (tr*16+l15), cols n = tc*16+quad*4+r.
    auto computeScoreT = [&](f32x4 (&acc)[2][4], const unsigned short* ksrc) {
        #pragma unroll
        for (int ks = 0; ks < 2; ++ks) {
            const int cu = ks * 32 + quad * 8;
            short8 af[2];
            #pragma unroll
            for (int tr = 0; tr < 2; ++tr)
                af[tr] = *(const short8*)&Qs[(rowA + tr * 16 + l15) * LDK + cu];
            #pragma unroll
            for (int tc = 0; tc < 4; ++tc) {
                short8 bfr = *(const short8*)&ksrc[(tc * 16 + l15) * LDK + cu];
                #pragma unroll
                for (int tr = 0; tr < 2; ++tr)
                    acc[tr][tc] = __builtin_amdgcn_mfma_f32_16x16x32_bf16(bfr, af[tr], acc[tr][tc], 0, 0, 0);
            }
        }
    };

    const f32x4 zero4 = {0.f, 0.f, 0.f, 0.f};

    for (int pass = 0; pass < 2; ++pass) {
        const int rt = (pass == 0) ? rty : (7 - rty);
        const int m0 = rt * TM;

        // Protect Qs/Ks/Vs/Ps against stragglers still reading them in the
        // previous pass (pass 0: trivially satisfied).
        barrier_lds();

        // ---- stage Q tile (once per pass): coalesced float4, cvt bf16 ----
        #pragma unroll
        for (int i = 0; i < 8; ++i) {
            int idx = (i * 256 + t) * 4;            // 0..8191
            int m = idx >> 6, c = idx & 63;
            float4 f = *(const float4*)&qb[(size_t)(m0 + m) * D_ + c];
            ushort4 b;
            b.x = bf16r(f.x); b.y = bf16r(f.y); b.z = bf16r(f.z); b.w = bf16r(f.w);
            *(ushort4*)&Qs[m * LDK + c] = b;
        }

        // ================= Phase 1: row sums Z (triangular sweep) =================
        float zpart[2][4] = {};
        const int ntmax1 = (m0 + TM - 1) / TN;      // last tile touching the diagonal
        loadK(0); writeK(Ks[0]);                    // prologue stage
        for (int nt = 0; nt <= ntmax1; ++nt) {
            barrier_lds();                          // Ks[nt&1] (and Qs at nt=0) visible;
                                                    // all waves done reading Ks[(nt+1)&1]
            if (nt < ntmax1) loadK(nt + 1);         // in flight during compute below
            f32x4 acc[2][4];
            #pragma unroll
            for (int tr = 0; tr < 2; ++tr)
                #pragma unroll
                for (int tc = 0; tc < 4; ++tc) acc[tr][tc] = zero4;
            computeScoreT(acc, Ks[nt & 1]);
            #pragma unroll
            for (int tr = 0; tr < 2; ++tr) {
                const int gm = m0 + rowA + tr * 16 + l15;
                #pragma unroll
                for (int tc = 0; tc < 4; ++tc)
                    #pragma unroll
                    for (int r = 0; r < 4; ++r) {
                        const int gn = nt * TN + tc * 16 + quad * 4 + r;
                        zpart[tr][tc] += (gn > gm) ? 1.0f : __expf(acc[tr][tc][r] * 0.125f);
                    }
            }
            if (nt < ntmax1) writeK(Ks[(nt + 1) & 1]);   // consume loads at region end
        }
        // Masked columns in tiles nt > ntmax1: each contributes exp(-1e-12) == 1.0f.
        const float zmissing = (float)(L_ - (ntmax1 + 1) * TN);

        loadK(0); loadV(0);                          // phase-2 prologue issue
        float rcpz[2];
        #pragma unroll
        for (int tr = 0; tr < 2; ++tr) {
            float z = (zpart[tr][0] + zpart[tr][1]) + (zpart[tr][2] + zpart[tr][3]);
            z += __shfl_xor(z, 16);                 // sum across quads (same l15)
            z += __shfl_xor(z, 32);
            rcpz[tr] = 1.0f / (z + zmissing);
        }
        barrier_lds();                              // all phase-1 reads of Ks done
        writeK(Ks[0]); writeV(Vs[0]);

        // ================= Phase 2: write attn, accumulate out = P @ V =================
        f32x4 oacc[2][4];
        #pragma unroll
        for (int tr = 0; tr < 2; ++tr)
            #pragma unroll
            for (int tc = 0; tc < 4; ++tc) oacc[tr][tc] = zero4;

        for (int nt = 0; nt < NT; ++nt) {
            const bool fullmask = (nt * TN) > (m0 + TM - 1);   // block-uniform
            barrier_lds();                          // bufs[nt&1] visible; prev reads of
                                                    // bufs[(nt+1)&1] done
            const int nn = nt + 1;
            const bool nextV = (nn < NT);
            const bool nextK = nextV && ((nn * TN) <= (m0 + TM - 1));
            if (nextV) loadV(nn);                   // in flight during everything below
            if (nextK) loadK(nn);

            if (!fullmask) {
                f32x4 acc[2][4];
                #pragma unroll
                for (int tr = 0; tr < 2; ++tr)
                    #pragma unroll
                    for (int tc = 0; tc < 4; ++tc) acc[tr][tc] = zero4;
                computeScoreT(acc, Ks[nt & 1]);
                #pragma unroll
                for (int tr = 0; tr < 2; ++tr) {
                    const int lrow = rowA + tr * 16 + l15;
                    const int gm = m0 + lrow;
                    const float rz = rcpz[tr];
                    #pragma unroll
                    for (int tc = 0; tc < 4; ++tc) {
                        float p[4];
                        #pragma unroll
                        for (int r = 0; r < 4; ++r) {
                            const int gn = nt * TN + tc * 16 + quad * 4 + r;
                            float e = (gn > gm) ? 1.0f : __expf(acc[tr][tc][r] * 0.125f);
                            p[r] = e * rz;
                        }
                        float4 vv = {p[0], p[1], p[2], p[3]};
                        *(float4*)&attnb[(size_t)gm * L_ + nt * TN + tc * 16 + quad * 4] = vv;
                        ushort4 pw;
                        pw.x = bf16r(p[0]); pw.y = bf16r(p[1]);
                        pw.z = bf16r(p[2]); pw.w = bf16r(p[3]);
                        *(ushort4*)&Ps[lrow * LDK + tc * 16 + quad * 4] = pw;
                    }
                }
            } else {
                // row-constant value 1/Z: broadcast stores; Ps content is nt-invariant
                const bool firstFull = (nt == ntmax1 + 1);
                #pragma unroll
                for (int tr = 0; tr < 2; ++tr) {
                    const int lrow = rowA + tr * 16 + l15;
                    const int gm = m0 + lrow;
                    const float rz = rcpz[tr];
                    float4 vv = {rz, rz, rz, rz};
                    const unsigned short pb = bf16r(rz);
                    ushort4 p4; p4.x = pb; p4.y = pb; p4.z = pb; p4.w = pb;
                    #pragma unroll
                    for (int c = 0; c < 4; ++c) {
                        *(float4*)&attnb[(size_t)gm * L_ + nt * TN + c * 16 + quad * 4] = vv;
                        if (firstFull)
                            *(ushort4*)&Ps[lrow * LDK + c * 16 + quad * 4] = p4;
                    }
                }
            }

            // NO barrier: PV's pf reads only THIS wave's 32 Ps rows.
            #pragma unroll
            for (int ks = 0; ks < 2; ++ks) {
                const int cu = ks * 32 + quad * 8;
                short8 pf[2];
                #pragma unroll
                for (int tr = 0; tr < 2; ++tr)
                    pf[tr] = *(const short8*)&Ps[(rowA + tr * 16 + l15) * LDK + cu];
                #pragma unroll
                for (int tc = 0; tc < 4; ++tc) {
                    short8 vf = *(const short8*)&Vs[nt & 1][(tc * 16 + l15) * LDK + cu];
                    #pragma unroll
                    for (int tr = 0; tr < 2; ++tr)
                        oacc[tr][tc] = __builtin_amdgcn_mfma_f32_16x16x32_bf16(pf[tr], vf, oacc[tr][tc], 0, 0, 0);
                }
            }

            if (nextV) writeV(Vs[nn & 1]);          // consume in-flight loads at region end
            if (nextK) writeK(Ks[nn & 1]);
        }

        // epilogue: store out for this pass (already normalized)
        #pragma unroll
        for (int tr = 0; tr < 2; ++tr)
            #pragma unroll
            for (int r = 0; r < 4; ++r) {
                const int gm = m0 + rowA + tr * 16 + quad * 4 + r;
                #pragma unroll
                for (int tc = 0; tc < 4; ++tc)
                    outb[(size_t)gm * D_ + tc * 16 + l15] = oacc[tr][tc][r];
            }
    }
}

extern "C" void kernel_launch(void* const* d_in, const int* in_sizes, int n_in,
                              void* d_out, int out_size, void* d_ws, size_t ws_size,
                              hipStream_t stream) {
    (void)in_sizes; (void)n_in; (void)d_ws; (void)ws_size; (void)out_size;
    const float* q = (const float*)d_in[0];
    const float* k = (const float*)d_in[1];
    const float* v = (const float*)d_in[2];
    // d_in[3] is the mask: it is tril(L,L) by construction; gn>gm reproduces it exactly.
    float* out  = (float*)d_out;
    float* attn = (float*)d_out + (size_t)8 * 16 * 1024 * 64;   // outputs concatenated (out, attn)
    dim3 grid(128, 4);   // x = bh (XCD = bh%8), y = rty; each block does rt={rty, 7-rty}
    sdpa_kernel<<<grid, dim3(256), 0, stream>>>(q, k, v, out, attn);
}